// Round 1
// baseline (120.678 us; speedup 1.0000x reference)
//
#include <hip/hip_runtime.h>
#include <hip/hip_bf16.h>
#include <cstdint>

#define N_PTS 8192
#define DIM 128

typedef __attribute__((ext_vector_type(8))) __bf16 bf16x8;
typedef __attribute__((ext_vector_type(4))) float f32x4;

// RNE float -> bf16 bits (inputs are finite, no NaN handling needed)
__device__ __forceinline__ unsigned short f2bf(float x) {
  unsigned int u = __float_as_uint(x);
  unsigned int r = (u + 0x7FFFu + ((u >> 16) & 1u)) >> 16;
  return (unsigned short)r;
}

// One wave per row: L2-normalize (eps=1e-12) and store bf16 bits.
__global__ __launch_bounds__(256) void normalize_kernel(const float* __restrict__ feat,
                                                        unsigned short* __restrict__ fb) {
  const int row = blockIdx.x * 4 + (threadIdx.x >> 6);
  const int lane = threadIdx.x & 63;
  const float2 v = *(const float2*)(feat + row * DIM + lane * 2);
  float ss = v.x * v.x + v.y * v.y;
#pragma unroll
  for (int o = 32; o > 0; o >>= 1) ss += __shfl_xor(ss, o);
  const float inv = 1.0f / fmaxf(sqrtf(ss), 1e-12f);
  const unsigned int pack =
      (unsigned int)f2bf(v.x * inv) | ((unsigned int)f2bf(v.y * inv) << 16);
  *(unsigned int*)(fb + row * DIM + lane * 2) = pack;
}

// 128x128 output tile per block (4 waves, each 64x64 = 4x4 MFMA tiles of 16x16).
// Computes sim = f @ f^T for the tile, then per-block online logsumexp partials
// for the positive and negative streams. partials[slot] = (Mp, Sp, Mn, Sn).
__global__ __launch_bounds__(256) void pair_kernel(const unsigned short* __restrict__ f,
                                                   const int* __restrict__ labels,
                                                   float4* __restrict__ partials) {
  const int tI = blockIdx.y, tJ = blockIdx.x;
  const int slot = tI * 64 + tJ;
  if (tJ < tI) {  // lower triangle: neutral partial
    if (threadIdx.x == 0) partials[slot] = make_float4(-1e30f, 0.f, -1e30f, 0.f);
    return;
  }

  __shared__ __align__(16) unsigned short sA[128 * 32];
  __shared__ __align__(16) unsigned short sB[128 * 32];
  __shared__ float redbuf[8];

  const int t = threadIdx.x;
  const int lane = t & 63, wave = t >> 6;
  const int wr = (wave >> 1) * 64, wc = (wave & 1) * 64;
  const int rsel = lane & 15, ksel = (lane >> 4) * 8;

  f32x4 acc[4][4];
#pragma unroll
  for (int a = 0; a < 4; ++a)
#pragma unroll
    for (int b = 0; b < 4; ++b) acc[a][b] = (f32x4){0.f, 0.f, 0.f, 0.f};

  const int rowA0 = tI * 128, rowB0 = tJ * 128;

  for (int kk = 0; kk < 4; ++kk) {
    const int k0 = kk * 32;
    if (kk) __syncthreads();
#pragma unroll
    for (int c0 = 0; c0 < 2; ++c0) {
      const int c = t + c0 * 256;           // 512 16B chunks per 128x32 slab
      const int r = c >> 2, e = (c & 3) * 8;
      *(uint4*)(&sA[r * 32 + e]) = *(const uint4*)(f + (rowA0 + r) * DIM + k0 + e);
      *(uint4*)(&sB[r * 32 + e]) = *(const uint4*)(f + (rowB0 + r) * DIM + k0 + e);
    }
    __syncthreads();
    bf16x8 fa[4], fbv[4];
#pragma unroll
    for (int x = 0; x < 4; ++x) {
      fa[x] = *(const bf16x8*)(&sA[(wr + x * 16 + rsel) * 32 + ksel]);
      fbv[x] = *(const bf16x8*)(&sB[(wc + x * 16 + rsel) * 32 + ksel]);
    }
#pragma unroll
    for (int tm = 0; tm < 4; ++tm)
#pragma unroll
      for (int tn = 0; tn < 4; ++tn)
        acc[tm][tn] =
            __builtin_amdgcn_mfma_f32_16x16x32_bf16(fa[tm], fbv[tn], acc[tm][tn], 0, 0, 0);
  }

  // ---- epilogue: circle-loss logits + online logsumexp ----
  // C/D mapping (16x16x32): col = lane&15, row = (lane>>4)*4 + reg
  const int ibase = tI * 128 + wr + (lane >> 4) * 4;
  const int jbase = tJ * 128 + wc + rsel;
  int li[4][4], lj[4];
#pragma unroll
  for (int tn = 0; tn < 4; ++tn) lj[tn] = labels[jbase + tn * 16];
#pragma unroll
  for (int tm = 0; tm < 4; ++tm)
#pragma unroll
    for (int r = 0; r < 4; ++r) li[tm][r] = labels[ibase + tm * 16 + r];

  // pass 1: per-thread maxes
  float mp = -1e30f, mn = -1e30f;
#pragma unroll
  for (int tm = 0; tm < 4; ++tm)
#pragma unroll
    for (int tn = 0; tn < 4; ++tn)
#pragma unroll
      for (int r = 0; r < 4; ++r) {
        const float s = acc[tm][tn][r];
        const bool valid = (jbase + tn * 16) > (ibase + tm * 16 + r);
        const bool eq = (li[tm][r] == lj[tn]);
        const float lp = fmaxf(1.25f - s, 0.f) * (0.75f - s) * 256.f;
        const float ln = fmaxf(s + 0.25f, 0.f) * (s - 0.25f) * 256.f;
        if (valid && eq) mp = fmaxf(mp, lp);
        if (valid && !eq) mn = fmaxf(mn, ln);
      }
#pragma unroll
  for (int o = 32; o > 0; o >>= 1) {
    mp = fmaxf(mp, __shfl_xor(mp, o));
    mn = fmaxf(mn, __shfl_xor(mn, o));
  }
  if (lane == 0) { redbuf[wave] = mp; redbuf[4 + wave] = mn; }
  __syncthreads();
  const float Mp = fmaxf(fmaxf(redbuf[0], redbuf[1]), fmaxf(redbuf[2], redbuf[3]));
  const float Mn = fmaxf(fmaxf(redbuf[4], redbuf[5]), fmaxf(redbuf[6], redbuf[7]));
  __syncthreads();  // protect redbuf before reuse for sums

  // pass 2: sums of exp(l - M)
  float sp = 0.f, sn = 0.f;
#pragma unroll
  for (int tm = 0; tm < 4; ++tm)
#pragma unroll
    for (int tn = 0; tn < 4; ++tn)
#pragma unroll
      for (int r = 0; r < 4; ++r) {
        const float s = acc[tm][tn][r];
        const bool valid = (jbase + tn * 16) > (ibase + tm * 16 + r);
        const bool eq = (li[tm][r] == lj[tn]);
        const float lp = fmaxf(1.25f - s, 0.f) * (0.75f - s) * 256.f;
        const float ln = fmaxf(s + 0.25f, 0.f) * (s - 0.25f) * 256.f;
        sp += __expf((valid && eq) ? (lp - Mp) : -1e30f);
        sn += __expf((valid && !eq) ? (ln - Mn) : -1e30f);
      }
#pragma unroll
  for (int o = 32; o > 0; o >>= 1) {
    sp += __shfl_xor(sp, o);
    sn += __shfl_xor(sn, o);
  }
  if (lane == 0) { redbuf[wave] = sp; redbuf[4 + wave] = sn; }
  __syncthreads();
  if (t == 0) {
    partials[slot] = make_float4(Mp, redbuf[0] + redbuf[1] + redbuf[2] + redbuf[3],
                                 Mn, redbuf[4] + redbuf[5] + redbuf[6] + redbuf[7]);
  }
}

// Merge 4096 (m,s) partials for both streams; softplus(lse_p + lse_n).
__global__ __launch_bounds__(256) void finalize_kernel(const float4* __restrict__ partials,
                                                       float* __restrict__ out) {
  const int t = threadIdx.x;
  float mp = -1e30f, sp = 0.f, mn = -1e30f, sn = 0.f;
  for (int i = t; i < 4096; i += 256) {
    const float4 p = partials[i];
    {
      const float m = fmaxf(mp, p.x);
      sp = sp * __expf(mp - m) + p.y * __expf(p.x - m);
      mp = m;
    }
    {
      const float m = fmaxf(mn, p.z);
      sn = sn * __expf(mn - m) + p.w * __expf(p.z - m);
      mn = m;
    }
  }
  __shared__ float smp[256], ssp[256], smn[256], ssn[256];
  smp[t] = mp; ssp[t] = sp; smn[t] = mn; ssn[t] = sn;
  __syncthreads();
  for (int off = 128; off > 0; off >>= 1) {
    if (t < off) {
      {
        const float m2 = smp[t + off], s2 = ssp[t + off];
        const float m = fmaxf(smp[t], m2);
        ssp[t] = ssp[t] * __expf(smp[t] - m) + s2 * __expf(m2 - m);
        smp[t] = m;
      }
      {
        const float m2 = smn[t + off], s2 = ssn[t + off];
        const float m = fmaxf(smn[t], m2);
        ssn[t] = ssn[t] * __expf(smn[t] - m) + s2 * __expf(m2 - m);
        smn[t] = m;
      }
    }
    __syncthreads();
  }
  if (t == 0) {
    const float lsep = smp[0] + __logf(ssp[0]);
    const float lsen = smn[0] + __logf(ssn[0]);
    const float x = lsep + lsen;
    out[0] = fmaxf(x, 0.f) + log1pf(__expf(-fabsf(x)));  // stable softplus
  }
}

extern "C" void kernel_launch(void* const* d_in, const int* in_sizes, int n_in,
                              void* d_out, int out_size, void* d_ws, size_t ws_size,
                              hipStream_t stream) {
  const float* feat = (const float*)d_in[0];
  const int* labels = (const int*)d_in[1];
  float* out = (float*)d_out;

  unsigned short* fb = (unsigned short*)d_ws;                        // 8192*128*2 = 2 MB
  float4* partials = (float4*)((char*)d_ws + (size_t)N_PTS * DIM * 2);  // 4096*16 = 64 KB

  normalize_kernel<<<N_PTS / 4, 256, 0, stream>>>(feat, fb);
  dim3 grid(64, 64);
  pair_kernel<<<grid, 256, 0, stream>>>(fb, labels, partials);
  finalize_kernel<<<1, 256, 0, stream>>>(partials, out);
}